// Round 7
// baseline (299.509 us; speedup 1.0000x reference)
//
#include <hip/hip_runtime.h>

typedef unsigned short ushort_t;
typedef unsigned int uint_t;
typedef __bf16 bf16x8 __attribute__((ext_vector_type(8)));
typedef float f32x16 __attribute__((ext_vector_type(16)));
typedef float f32x4 __attribute__((ext_vector_type(4)));
typedef short short8v __attribute__((ext_vector_type(8)));
typedef short short4v __attribute__((ext_vector_type(4)));

__device__ __forceinline__ ushort_t f2b(float f) {
    union { float f; uint_t i; } v; v.f = f;
    uint_t u = v.i;
    u += 0x7fffu + ((u >> 16) & 1u);
    return (ushort_t)(u >> 16);
}
__device__ __forceinline__ uint_t pack_bf2(float a, float b) {
    union { float f; uint_t u; } A, B; A.f = a; B.f = b;
    uint_t ua = A.u + (0x7fffu + ((A.u >> 16) & 1u));
    uint_t ub = B.u + (0x7fffu + ((B.u >> 16) & 1u));
    return (ua >> 16) | (ub & 0xffff0000u);
}
union V8 { short8v v; uint_t d[4]; };
__device__ __forceinline__ void unpack8(short8v vv, float* f) {
    V8 u; u.v = vv;
    #pragma unroll
    for (int i = 0; i < 4; ++i) {
        union { uint_t u; float f; } lo, hi;
        lo.u = u.d[i] << 16;
        hi.u = u.d[i] & 0xffff0000u;
        f[2 * i] = lo.f; f[2 * i + 1] = hi.f;
    }
}
__device__ __forceinline__ uint4 blend_pack(short8v a, short8v b, short8v c, short8v d,
                                            float w00, float w01, float w10, float w11) {
    float f00[8], f01[8], f10[8], f11[8], s[8];
    unpack8(a, f00); unpack8(b, f01); unpack8(c, f10); unpack8(d, f11);
    #pragma unroll
    for (int j = 0; j < 8; ++j)
        s[j] = w00 * f00[j] + w01 * f01[j] + w10 * f10[j] + w11 * f11[j];
    uint4 pk;
    pk.x = pack_bf2(s[0], s[1]); pk.y = pack_bf2(s[2], s[3]);
    pk.z = pack_bf2(s[4], s[5]); pk.w = pack_bf2(s[6], s[7]);
    return pk;
}
__device__ __forceinline__ void calc_corners(float py, float px, int chbase,
    float& w00, float& w01, float& w10, float& w11,
    int& o00, int& o01, int& o10, int& o11)
{
    float y0f = floorf(py), x0f = floorf(px);
    float wy = py - y0f, wx = px - x0f;
    int iy0 = (int)y0f, ix0 = (int)x0f;
    float fy0 = (iy0 >= 0 && iy0 < 64) ? 1.f : 0.f;
    float fy1 = (iy0 >= -1 && iy0 < 63) ? 1.f : 0.f;
    float fx0 = (ix0 >= 0 && ix0 < 64) ? 1.f : 0.f;
    float fx1 = (ix0 >= -1 && ix0 < 63) ? 1.f : 0.f;
    int cy0 = min(max(iy0, 0), 63), cy1 = min(max(iy0 + 1, 0), 63);
    int cx0 = min(max(ix0, 0), 63), cx1 = min(max(ix0 + 1, 0), 63);
    w00 = (1.f - wy) * (1.f - wx) * fy0 * fx0;
    w01 = (1.f - wy) * wx * fy0 * fx1;
    w10 = wy * (1.f - wx) * fy1 * fx0;
    w11 = wy * wx * fy1 * fx1;
    o00 = (cy0 * 64 + cx0) * 128 + chbase;
    o01 = (cy0 * 64 + cx1) * 128 + chbase;
    o10 = (cy1 * 64 + cx0) * 128 + chbase;
    o11 = (cy1 * 64 + cx1) * 128 + chbase;
}

// ---------------- xt: NCHW fp32 -> NHWC bf16 (vectorized) + weight packing ----------------
__global__ __launch_bounds__(256) void xt_prep_kernel(
    const float* __restrict__ x, ushort_t* __restrict__ xt,
    const float* __restrict__ deform_w,   // (128,128,3,3)
    const float* __restrict__ offset_w,   // (18,128,3,3)
    const float* __restrict__ gamma,
    const float* __restrict__ beta,
    const float* __restrict__ rmean,
    const float* __restrict__ rvar,
    ushort_t* __restrict__ wA,    // [p][cout][c] bf16
    ushort_t* __restrict__ wOb,   // [32 (18 used)][k=tap*128+c] bf16
    float* __restrict__ scale,
    float* __restrict__ shift)
{
    __shared__ __align__(16) ushort_t tile[128 * 66];   // [c][w], +2 pad
    int braw = blockIdx.x;
    int b = ((braw & 7) << 7) + (braw >> 3);   // XCD slab swizzle
    int n = b >> 6, h = b & 63;
    int t = threadIdx.x;

    int i = braw * 256 + t;
    if (i < 147456) {
        int p = i >> 14, o = (i >> 7) & 127, c = i & 127;
        wA[i] = f2b(deform_w[o * 1152 + c * 9 + p]);
    }
    if (i < 36864) {
        int row = i / 1152;
        int k = i - row * 1152;
        int tap = k >> 7, c = k & 127;
        wOb[i] = (row < 18) ? f2b(offset_w[row * 1152 + c * 9 + tap]) : (ushort_t)0;
    }
    if (i < 128) {
        float sc = gamma[i] * rsqrtf(rvar[i] + 1e-5f);
        scale[i] = sc;
        shift[i] = beta[i] - rmean[i] * sc;
    }

    // load: 128 c-rows x 64 w as float4 (2048 chunks, 8/thread), coalesced
    const float* xb = x + ((long)(n * 128) * 64 + h) * 64;
    #pragma unroll
    for (int it = 0; it < 8; ++it) {
        int idx = it * 256 + t;
        int c = idx >> 4, w4 = (idx & 15) << 2;
        float4 f = *(const float4*)(xb + c * 4096 + w4);
        ushort4 v = make_ushort4(f2b(f.x), f2b(f.y), f2b(f.z), f2b(f.w));
        *(ushort4*)(&tile[c * 66 + w4]) = v;
    }
    __syncthreads();
    // write: [w][c-chunks of 8] -> 16B global stores, coalesced
    #pragma unroll
    for (int it = 0; it < 4; ++it) {
        int idx = it * 256 + t;
        int w = idx >> 4, cg = (idx & 15) << 3;
        ushort_t tmp[8];
        #pragma unroll
        for (int j = 0; j < 8; ++j) tmp[j] = tile[(cg + j) * 66 + w];
        *(short8v*)(xt + ((n * 64 + h) * 64 + w) * 128 + cg) = *(short8v*)(tmp);
    }
}

// ---------------- offset conv: pure MFMA GEMM, no LDS, B straight from xt (L2) ----------------
// block = (n, ho); M=32(18 used) x N=64pix x K=1152
__global__ __launch_bounds__(256) void offconv_kernel(
    const ushort_t* __restrict__ xt,      // (16,64,64,128) bf16
    const ushort_t* __restrict__ wOb,     // [32][1152] bf16
    const float* __restrict__ offset_b,   // (18,)
    float* __restrict__ off_pos)          // (16,18,64,64) fp32
{
    int braw = blockIdx.x;
    int b = ((braw & 7) << 7) + (braw >> 3);
    int n = b >> 6, ho = b & 63;
    int t = threadIdx.x;
    int lane = t & 63;
    int wv = __builtin_amdgcn_readfirstlane(t >> 6);
    int m = lane & 15, kq = lane >> 4;
    int pixq = wv * 16 + m;
    const ushort_t* xn = xt + n * (64 * 64 * 128);

    f32x4 acc[2];
    #pragma unroll
    for (int mt = 0; mt < 2; ++mt)
        #pragma unroll
        for (int r = 0; r < 4; ++r) acc[mt][r] = 0.f;

    #pragma unroll
    for (int ks = 0; ks < 36; ++ks) {
        const int tap = ks >> 2, cq = ks & 3;
        const int krow = tap / 3, kx = tap % 3;
        bf16x8 a0 = *(const bf16x8*)(wOb + m * 1152 + tap * 128 + cq * 32 + kq * 8);
        bf16x8 a1 = *(const bf16x8*)(wOb + (m + 16) * 1152 + tap * 128 + cq * 32 + kq * 8);
        int row = ho + krow - 1;
        int col = pixq + kx - 1;
        bf16x8 bv = {0, 0, 0, 0, 0, 0, 0, 0};
        if (row >= 0 && row < 64 && col >= 0 && col < 64)
            bv = *(const bf16x8*)(xn + (row * 64 + col) * 128 + cq * 32 + kq * 8);
        acc[0] = __builtin_amdgcn_mfma_f32_16x16x32_bf16(a0, bv, acc[0], 0, 0, 0);
        acc[1] = __builtin_amdgcn_mfma_f32_16x16x32_bf16(a1, bv, acc[1], 0, 0, 0);
    }

    #pragma unroll
    for (int mt = 0; mt < 2; ++mt)
        #pragma unroll
        for (int r = 0; r < 4; ++r) {
            int oc = mt * 16 + kq * 4 + r;
            if (oc < 18) {
                float v = acc[mt][r] + offset_b[oc];
                int pp = oc >> 1;
                v += (oc & 1) ? (float)(pp % 3 - 1 + pixq) : (float)(pp / 3 - 1 + ho);
                off_pos[((n * 18 + oc) * 64 + ho) * 64 + pixq] = v;
            }
        }
}

// ---------------- deform: bilinear sample + MFMA GEMM + BN + SiLU ----------------
// 1-row blocks, 32 KiB LDS double-buffer, 4 blocks/CU (grid fully resident)
__global__ __launch_bounds__(256, 4) void deform_kernel(
    const ushort_t* __restrict__ xt,      // (16,64,64,128) bf16
    const float* __restrict__ off_pos,    // (16,18,64,64) fp32
    const ushort_t* __restrict__ wA,      // [p][cout][c] bf16
    const float* __restrict__ scale,
    const float* __restrict__ shift,
    float* __restrict__ out)              // (16,128,64,64) fp32
{
    __shared__ __align__(16) ushort_t S[2 * 64 * 128];  // 32 KiB
    int braw = blockIdx.x;
    int b = ((braw & 7) << 7) + (braw >> 3);   // XCD slab swizzle
    int n = b >> 6, ho = b & 63;
    int t = threadIdx.x;
    int lane = t & 63;
    int wv = __builtin_amdgcn_readfirstlane(t >> 6);
    int pix_s = lane;
    int chbase = wv * 32;
    int mh = wv >> 1, nh = wv & 1;

    const ushort_t* xn = xt + n * (64 * 64 * 128);
    const float* opn = off_pos + ((long)(n * 18) * 64 + ho) * 64 + pix_s;

    f32x16 acc[2];
    #pragma unroll
    for (int mt = 0; mt < 2; ++mt)
        #pragma unroll
        for (int r = 0; r < 16; ++r) acc[mt][r] = 0.f;

    float w00, w01, w10, w11;
    int o00, o01, o10, o11;
    short8v v00[2], v01[2], v10[2], v11[2];

    calc_corners(opn[0], opn[4096], chbase, w00, w01, w10, w11, o00, o01, o10, o11);
    #pragma unroll
    for (int g = 0; g < 2; ++g) {
        v00[g] = *(const short8v*)(xn + o00 + g * 8);
        v01[g] = *(const short8v*)(xn + o01 + g * 8);
        v10[g] = *(const short8v*)(xn + o10 + g * 8);
        v11[g] = *(const short8v*)(xn + o11 + g * 8);
    }

    for (int p = 0; p < 9; ++p) {
        ushort_t* buf = S + (p & 1) * 8192;

        short8v u00[2], u01[2], u10[2], u11[2];
        #pragma unroll
        for (int g = 0; g < 2; ++g) {
            u00[g] = *(const short8v*)(xn + o00 + (g + 2) * 8);
            u01[g] = *(const short8v*)(xn + o01 + (g + 2) * 8);
            u10[g] = *(const short8v*)(xn + o10 + (g + 2) * 8);
            u11[g] = *(const short8v*)(xn + o11 + (g + 2) * 8);
        }
        #pragma unroll
        for (int g = 0; g < 2; ++g) {
            uint4 pk = blend_pack(v00[g], v01[g], v10[g], v11[g], w00, w01, w10, w11);
            int gg = (wv * 4 + g) ^ (pix_s & 15);
            *(uint4*)(buf + pix_s * 128 + gg * 8) = pk;
        }
        #pragma unroll
        for (int g = 0; g < 2; ++g) {
            uint4 pk = blend_pack(u00[g], u01[g], u10[g], u11[g], w00, w01, w10, w11);
            int gg = (wv * 4 + g + 2) ^ (pix_s & 15);
            *(uint4*)(buf + pix_s * 128 + gg * 8) = pk;
        }

        if (p < 8) {   // prefetch next p's positions + first-half corners
            calc_corners(opn[(2 * p + 2) * 4096], opn[(2 * p + 3) * 4096],
                         chbase, w00, w01, w10, w11, o00, o01, o10, o11);
            #pragma unroll
            for (int g = 0; g < 2; ++g) {
                v00[g] = *(const short8v*)(xn + o00 + g * 8);
                v01[g] = *(const short8v*)(xn + o01 + g * 8);
                v10[g] = *(const short8v*)(xn + o10 + g * 8);
                v11[g] = *(const short8v*)(xn + o11 + g * 8);
            }
        }

        // a0-fragments prefetched pre-barrier (in flight across the barrier)
        const ushort_t* wAp = wA + p * 16384;
        int coutA = mh * 64 + (lane & 31);
        bf16x8 a0f[8];
        #pragma unroll
        for (int ks = 0; ks < 8; ++ks)
            a0f[ks] = *(const bf16x8*)(wAp + coutA * 128 + ks * 16 + ((lane >> 5) << 3));

        __syncthreads();   // stores to buf visible; prior-p readers done (alt buffer)

        int pixb = nh * 32 + (lane & 31);
        #pragma unroll
        for (int ks = 0; ks < 8; ++ks) {
            bf16x8 a1 = *(const bf16x8*)(wAp + (coutA + 32) * 128 + ks * 16 + ((lane >> 5) << 3));
            int gg = (ks * 2 + (lane >> 5)) ^ (pixb & 15);
            bf16x8 bfrag = *(const bf16x8*)(buf + pixb * 128 + gg * 8);
            acc[0] = __builtin_amdgcn_mfma_f32_32x32x16_bf16(a0f[ks], bfrag, acc[0], 0, 0, 0);
            acc[1] = __builtin_amdgcn_mfma_f32_32x32x16_bf16(a1, bfrag, acc[1], 0, 0, 0);
        }
    }

    // ---- epilogue: BN + SiLU ----
    int pixb = nh * 32 + (lane & 31);
    #pragma unroll
    for (int mt = 0; mt < 2; ++mt) {
        #pragma unroll
        for (int r = 0; r < 16; ++r) {
            int cout = mh * 64 + mt * 32 + (r & 3) + 8 * (r >> 2) + 4 * (lane >> 5);
            float v = acc[mt][r] * scale[cout] + shift[cout];
            float rr = v / (1.f + __expf(-v));
            out[((n * 128 + cout) * 64 + ho) * 64 + pixb] = rr;
        }
    }
}

extern "C" void kernel_launch(void* const* d_in, const int* in_sizes, int n_in,
                              void* d_out, int out_size, void* d_ws, size_t ws_size,
                              hipStream_t stream) {
    const float* x        = (const float*)d_in[0];
    const float* offset_w = (const float*)d_in[1];
    const float* offset_b = (const float*)d_in[2];
    const float* deform_w = (const float*)d_in[3];
    const float* gamma    = (const float*)d_in[4];
    const float* beta     = (const float*)d_in[5];
    const float* rmean    = (const float*)d_in[6];
    const float* rvar     = (const float*)d_in[7];

    char* ws = (char*)d_ws;
    float*    off_pos = (float*)(ws);                //  4,718,592 B
    ushort_t* xt    = (ushort_t*)(ws + 4718592);     // 16,777,216 B
    ushort_t* wA    = (ushort_t*)(ws + 21495808);    //    294,912 B
    ushort_t* wOb   = (ushort_t*)(ws + 21790720);    //     73,728 B
    float*    scale = (float*)(ws + 21864448);       //        512 B
    float*    shift = (float*)(ws + 21864960);       //        512 B
    float*    out   = (float*)d_out;

    hipLaunchKernelGGL(xt_prep_kernel, dim3(1024), dim3(256), 0, stream,
                       x, xt, deform_w, offset_w, gamma, beta, rmean, rvar,
                       wA, wOb, scale, shift);
    hipLaunchKernelGGL(offconv_kernel, dim3(1024), dim3(256), 0, stream,
                       xt, wOb, offset_b, off_pos);
    hipLaunchKernelGGL(deform_kernel, dim3(1024), dim3(256), 0, stream,
                       xt, off_pos, wA, scale, shift, out);
}